// Round 1
// baseline (63.729 us; speedup 1.0000x reference)
//
#include <hip/hip_runtime.h>

// tanh(x) = 1 - 2/(e^{2x}+1); exact at +-inf, ~1e-6 abs error.
__device__ __forceinline__ float fast_tanh(float x) {
    float e = __builtin_amdgcn_exp2f(x * 2.8853901817779268f); // e^{2x} = 2^{2x*log2(e)}
    float r = __builtin_amdgcn_rcpf(e + 1.0f);
    return fmaf(-2.0f, r, 1.0f);
}

// One thread per (edge, class). Lane's class c = tid & 3.
// Per-class weights (49 floats) held in VGPRs, amortized over a grid-stride loop.
__global__ __launch_bounds__(256) void edge_mlp(
    const float* __restrict__ m,     // [N_NODES, 4, 2]
    const int*   __restrict__ eidx,  // [2, E] (int32 per harness convention)
    const float* __restrict__ W1,    // [4, 4, 8]
    const float* __restrict__ b1,    // [4, 8]
    const float* __restrict__ W2,    // [4, 8, 1]
    const float* __restrict__ b2,    // [4, 1]
    float*       __restrict__ out,   // [E, 4]
    const int nE)
{
    const int tid0 = blockIdx.x * blockDim.x + threadIdx.x;
    const int c = tid0 & 3;

    // ---- load this lane's class weights into registers (once) ----
    float w1[32];                       // W1[c][i][j] at w1[i*8 + j]
    #pragma unroll
    for (int k = 0; k < 8; ++k)
        *(float4*)(&w1[4*k]) = *(const float4*)(W1 + c*32 + 4*k);
    float bb1[8];
    *(float4*)(&bb1[0]) = *(const float4*)(b1 + c*8);
    *(float4*)(&bb1[4]) = *(const float4*)(b1 + c*8 + 4);
    float w2[8];
    *(float4*)(&w2[0]) = *(const float4*)(W2 + c*8);
    *(float4*)(&w2[4]) = *(const float4*)(W2 + c*8 + 4);
    const float b2s = b2[c];

    const int total  = nE * 4;
    const int stride = gridDim.x * blockDim.x;    // multiple of 4 -> c constant per thread

    #pragma unroll 2
    for (int t = tid0; t < total; t += stride) {
        const int e   = t >> 2;
        const int row = eidx[e];        // edge_index[0][e]
        const int col = eidx[nE + e];   // edge_index[1][e]

        // B = concat(m[col], m[row]) ; this lane needs only class c's slice (2+2 floats)
        const float2 mc = *(const float2*)(m + (size_t)col * 8 + c * 2);
        const float2 mr = *(const float2*)(m + (size_t)row * 8 + c * 2);

        float o = b2s;
        #pragma unroll
        for (int j = 0; j < 8; ++j) {
            float h = bb1[j];
            h = fmaf(mc.x, w1[j],      h);
            h = fmaf(mc.y, w1[8 + j],  h);
            h = fmaf(mr.x, w1[16 + j], h);
            h = fmaf(mr.y, w1[24 + j], h);
            o = fmaf(fast_tanh(h), w2[j], o);
        }
        o = fast_tanh(o);

        // softmax over the 4 classes: quad lives in lanes (t&~3)..(t&~3)+3
        const float eo = __builtin_amdgcn_exp2f(o * 1.4426950408889634f); // e^o
        float s = eo + __shfl_xor(eo, 1);
        s += __shfl_xor(s, 2);
        out[t] = eo * __builtin_amdgcn_rcpf(s);
    }
}

extern "C" void kernel_launch(void* const* d_in, const int* in_sizes, int n_in,
                              void* d_out, int out_size, void* d_ws, size_t ws_size,
                              hipStream_t stream) {
    const float* m  = (const float*)d_in[0];
    const int* eidx = (const int*)d_in[1];
    const float* W1 = (const float*)d_in[2];
    const float* b1 = (const float*)d_in[3];
    const float* W2 = (const float*)d_in[4];
    const float* b2 = (const float*)d_in[5];
    float* out = (float*)d_out;
    const int nE = in_sizes[1] / 2;   // edge_index has 2*E elements

    const int threads = 256;
    const int blocks  = 2048;         // grid-stride: ~24 edges per thread
    hipLaunchKernelGGL(edge_mlp, dim3(blocks), dim3(threads), 0, stream,
                       m, eidx, W1, b1, W2, b2, out, nE);
}

// Round 2
// 60.913 us; speedup vs baseline: 1.0462x; 1.0462x over previous
//
#include <hip/hip_runtime.h>

// tanh(x) = 1 - 2/(e^{2x}+1); exact at +-inf, ~1e-6 abs error.
__device__ __forceinline__ float fast_tanh(float x) {
    float e = __builtin_amdgcn_exp2f(x * 2.8853901817779268f); // e^{2x} = 2^{2x*log2(e)}
    float r = __builtin_amdgcn_rcpf(e + 1.0f);
    return fmaf(-2.0f, r, 1.0f);
}

// One thread per (edge, class); lane's class c = tid & 3.
// __launch_bounds__(256,4): VGPR cap ~128 so the 49-float weight set stays
// register-resident (at (256,default) the compiler chose 36 VGPR and re-loaded
// weights every iteration — R1's latency bottleneck).
__global__ __launch_bounds__(256, 4) void edge_mlp(
    const float* __restrict__ m,     // [N_NODES, 4, 2]
    const int*   __restrict__ eidx,  // [2, E]
    const float* __restrict__ W1,    // [4, 4, 8]
    const float* __restrict__ b1,    // [4, 8]
    const float* __restrict__ W2,    // [4, 8, 1]
    const float* __restrict__ b2,    // [4, 1]
    float*       __restrict__ out,   // [E, 4]
    const int nE)
{
    const int tid0 = blockIdx.x * blockDim.x + threadIdx.x;
    const int c = tid0 & 3;
    const int cc2 = c * 2;

    // ---- per-class weights -> VGPRs (once per thread) ----
    float w1[32];                       // W1[c][i][j] at w1[i*8 + j]
    #pragma unroll
    for (int k = 0; k < 8; ++k)
        *(float4*)(&w1[4*k]) = *(const float4*)(W1 + c*32 + 4*k);
    float bb1[8];
    *(float4*)(&bb1[0]) = *(const float4*)(b1 + c*8);
    *(float4*)(&bb1[4]) = *(const float4*)(b1 + c*8 + 4);
    float w2[8];
    *(float4*)(&w2[0]) = *(const float4*)(W2 + c*8);
    *(float4*)(&w2[4]) = *(const float4*)(W2 + c*8 + 4);
    const float b2s = b2[c];

    const int total  = nE * 4;
    const int stride = gridDim.x * blockDim.x;   // multiple of 4 -> c constant per thread

    constexpr int UN = 4;
    int t = tid0;

    // ---- main loop: 4 independent gather chains in flight ----
    for (; t + (UN - 1) * stride < total; t += UN * stride) {
        int row[UN], col[UN];
        #pragma unroll
        for (int k = 0; k < UN; ++k) {
            const int e = (t + k * stride) >> 2;
            row[k] = __builtin_nontemporal_load(eidx + e);       // streaming: don't pollute L2
            col[k] = __builtin_nontemporal_load(eidx + nE + e);
        }
        float2 mc[UN], mr[UN];
        #pragma unroll
        for (int k = 0; k < UN; ++k) {
            mc[k] = *(const float2*)(m + (unsigned)col[k] * 8u + cc2);
            mr[k] = *(const float2*)(m + (unsigned)row[k] * 8u + cc2);
        }
        #pragma unroll
        for (int k = 0; k < UN; ++k) {
            float o = b2s;
            #pragma unroll
            for (int j = 0; j < 8; ++j) {
                float h = bb1[j];
                h = fmaf(mc[k].x, w1[j],      h);
                h = fmaf(mc[k].y, w1[8 + j],  h);
                h = fmaf(mr[k].x, w1[16 + j], h);
                h = fmaf(mr[k].y, w1[24 + j], h);
                o = fmaf(fast_tanh(h), w2[j], o);
            }
            o = fast_tanh(o);
            // softmax over the 4 classes (quad = lanes sharing t>>2)
            const float eo = __builtin_amdgcn_exp2f(o * 1.4426950408889634f); // e^o
            float s = eo + __shfl_xor(eo, 1);
            s += __shfl_xor(s, 2);
            __builtin_nontemporal_store(eo * __builtin_amdgcn_rcpf(s), out + (t + k * stride));
        }
    }

    // ---- tail ----
    for (; t < total; t += stride) {
        const int e   = t >> 2;
        const int row = eidx[e];
        const int col = eidx[nE + e];
        const float2 mc = *(const float2*)(m + (unsigned)col * 8u + cc2);
        const float2 mr = *(const float2*)(m + (unsigned)row * 8u + cc2);
        float o = b2s;
        #pragma unroll
        for (int j = 0; j < 8; ++j) {
            float h = bb1[j];
            h = fmaf(mc.x, w1[j],      h);
            h = fmaf(mc.y, w1[8 + j],  h);
            h = fmaf(mr.x, w1[16 + j], h);
            h = fmaf(mr.y, w1[24 + j], h);
            o = fmaf(fast_tanh(h), w2[j], o);
        }
        o = fast_tanh(o);
        const float eo = __builtin_amdgcn_exp2f(o * 1.4426950408889634f);
        float s = eo + __shfl_xor(eo, 1);
        s += __shfl_xor(s, 2);
        out[t] = eo * __builtin_amdgcn_rcpf(s);
    }
}

extern "C" void kernel_launch(void* const* d_in, const int* in_sizes, int n_in,
                              void* d_out, int out_size, void* d_ws, size_t ws_size,
                              hipStream_t stream) {
    const float* m  = (const float*)d_in[0];
    const int* eidx = (const int*)d_in[1];
    const float* W1 = (const float*)d_in[2];
    const float* b1 = (const float*)d_in[3];
    const float* W2 = (const float*)d_in[4];
    const float* b2 = (const float*)d_in[5];
    float* out = (float*)d_out;
    const int nE = in_sizes[1] / 2;   // edge_index has 2*E elements

    const int threads = 256;
    const int blocks  = 2048;         // grid-stride: ~6 unroll-4 iterations per thread
    hipLaunchKernelGGL(edge_mlp, dim3(blocks), dim3(threads), 0, stream,
                       m, eidx, W1, b1, W2, b2, out, nE);
}

// Round 4
// 60.592 us; speedup vs baseline: 1.0518x; 1.0053x over previous
//
#include <hip/hip_runtime.h>

#define TWO_LOG2E 2.8853901817779268f   // 2*log2(e)
#define LOG2E     1.4426950408889634f

// quad_perm DPP cross-lane (stays on VALU; __shfl_xor would lower to ds_swizzle)
template<int CTRL>
__device__ __forceinline__ float dpp_qperm(float x) {
    int r = __builtin_amdgcn_update_dpp(0, __float_as_int(x), CTRL, 0xF, 0xF, true);
    return __int_as_float(r);
}

// input hs = 2*log2(e)*x (prescaled); returns tanh(x) = 1 - 2/(e^{2x}+1)
__device__ __forceinline__ float tanh_pre(float hs) {
    float e = __builtin_amdgcn_exp2f(hs);
    float r = __builtin_amdgcn_rcpf(e + 1.0f);
    return fmaf(-2.0f, r, 1.0f);
}

// One thread per (edge, class); lane's class c = tid & 3.
// Weights prescaled by 2*log2e and PINNED into VGPRs via empty inline-asm so the
// compiler cannot rematerialize the loads inside the loop (R2: VGPR=52 showed it
// was re-loading all 49 weight floats every iteration).
__global__ __launch_bounds__(256, 4) void edge_mlp(
    const float* __restrict__ m,     // [N_NODES, 4, 2]
    const int*   __restrict__ eidx,  // [2, E]
    const float* __restrict__ W1,    // [4, 4, 8]
    const float* __restrict__ b1,    // [4, 8]
    const float* __restrict__ W2,    // [4, 8, 1]
    const float* __restrict__ b2,    // [4, 1]
    float*       __restrict__ out,   // [E, 4]
    const int nE)
{
    const int tid0 = blockIdx.x * blockDim.x + threadIdx.x;
    const int c = tid0 & 3;
    const int cc2 = c * 2;

    // ---- per-class weights -> VGPRs, prescaled by 2*log2e ----
    float w1[32];                       // W1[c][i][j] * 2log2e at w1[i*8+j]
    #pragma unroll
    for (int k = 0; k < 8; ++k) {
        float4 v = *(const float4*)(W1 + c*32 + 4*k);
        w1[4*k+0] = v.x * TWO_LOG2E; w1[4*k+1] = v.y * TWO_LOG2E;
        w1[4*k+2] = v.z * TWO_LOG2E; w1[4*k+3] = v.w * TWO_LOG2E;
    }
    float bb1[8];
    #pragma unroll
    for (int j = 0; j < 8; ++j) bb1[j] = b1[c*8 + j] * TWO_LOG2E;
    float w2[8];
    #pragma unroll
    for (int j = 0; j < 8; ++j) w2[j] = W2[c*8 + j] * TWO_LOG2E;
    float b2s = b2[c] * TWO_LOG2E;

    // pin: compiler must keep these live in VGPRs (no remat/reload in loop)
    #pragma unroll
    for (int i = 0; i < 32; ++i) asm volatile("" : "+v"(w1[i]));
    #pragma unroll
    for (int j = 0; j < 8; ++j)  asm volatile("" : "+v"(bb1[j]));
    #pragma unroll
    for (int j = 0; j < 8; ++j)  asm volatile("" : "+v"(w2[j]));
    asm volatile("" : "+v"(b2s));

    const int* eidx1 = eidx + nE;
    const int total  = nE * 4;
    const int stride = gridDim.x * blockDim.x;   // multiple of 4 -> c constant

    constexpr int UN = 4;
    int t = tid0;

    for (; t + (UN - 1) * stride < total; t += UN * stride) {
        int row[UN], col[UN];
        #pragma unroll
        for (int k = 0; k < UN; ++k) {
            const int e = (t + k * stride) >> 2;
            row[k] = __builtin_nontemporal_load(eidx + e);
            col[k] = __builtin_nontemporal_load(eidx1 + e);
        }
        float2 mc[UN], mr[UN];
        #pragma unroll
        for (int k = 0; k < UN; ++k) {
            mc[k] = *(const float2*)(m + (unsigned)col[k] * 8u + cc2);
            mr[k] = *(const float2*)(m + (unsigned)row[k] * 8u + cc2);
        }
        #pragma unroll
        for (int k = 0; k < UN; ++k) {
            float o = b2s;                      // scaled domain (×2log2e)
            #pragma unroll
            for (int j = 0; j < 8; ++j) {
                float h = bb1[j];               // all scaled by 2log2e
                h = fmaf(mc[k].x, w1[j],      h);
                h = fmaf(mc[k].y, w1[8 + j],  h);
                h = fmaf(mr[k].x, w1[16 + j], h);
                h = fmaf(mr[k].y, w1[24 + j], h);
                o = fmaf(tanh_pre(h), w2[j], o);  // tanh true-valued, o scaled
            }
            const float to = tanh_pre(o);       // o already ×2log2e
            // softmax over the 4 classes (quad), pure-VALU DPP reduction
            const float eo = __builtin_amdgcn_exp2f(to * LOG2E);
            float s = eo + dpp_qperm<0xB1>(eo);     // xor 1
            s = s + dpp_qperm<0x4E>(s);             // xor 2
            __builtin_nontemporal_store(eo * __builtin_amdgcn_rcpf(s),
                                        out + (t + k * stride));
        }
    }

    // tail
    for (; t < total; t += stride) {
        const int e = t >> 2;
        const int r0 = eidx[e];
        const int c0 = eidx1[e];
        const float2 mcv = *(const float2*)(m + (unsigned)c0 * 8u + cc2);
        const float2 mrv = *(const float2*)(m + (unsigned)r0 * 8u + cc2);
        float o = b2s;
        #pragma unroll
        for (int j = 0; j < 8; ++j) {
            float h = bb1[j];
            h = fmaf(mcv.x, w1[j],      h);
            h = fmaf(mcv.y, w1[8 + j],  h);
            h = fmaf(mrv.x, w1[16 + j], h);
            h = fmaf(mrv.y, w1[24 + j], h);
            o = fmaf(tanh_pre(h), w2[j], o);
        }
        const float to = tanh_pre(o);
        const float eo = __builtin_amdgcn_exp2f(to * LOG2E);
        float s = eo + dpp_qperm<0xB1>(eo);
        s = s + dpp_qperm<0x4E>(s);
        out[t] = eo * __builtin_amdgcn_rcpf(s);
    }
}

extern "C" void kernel_launch(void* const* d_in, const int* in_sizes, int n_in,
                              void* d_out, int out_size, void* d_ws, size_t ws_size,
                              hipStream_t stream) {
    const float* m  = (const float*)d_in[0];
    const int* eidx = (const int*)d_in[1];
    const float* W1 = (const float*)d_in[2];
    const float* b1 = (const float*)d_in[3];
    const float* W2 = (const float*)d_in[4];
    const float* b2 = (const float*)d_in[5];
    float* out = (float*)d_out;
    const int nE = in_sizes[1] / 2;

    const int threads = 256;
    const int blocks  = 2048;
    hipLaunchKernelGGL(edge_mlp, dim3(blocks), dim3(threads), 0, stream,
                       m, eidx, W1, b1, W2, b2, out, nE);
}